// Round 1
// baseline (828.243 us; speedup 1.0000x reference)
//
#include <hip/hip_runtime.h>
#include <hip/hip_bf16.h>

// Problem constants (MoE grouped FFN, uniform groups)
#define NE 32      // experts
#define HD 2048    // hidden
#define ID 1024    // intermediate
#define GT 1024    // tokens per expert (T/E = 32768/32)

// Tile config
#define BM 128
#define BN 128
#define BK 64
#define PAD 8
#define LDK (BK + PAD)   // 72 elems -> 144 B row stride (16B-aligned)

typedef __attribute__((ext_vector_type(8))) __bf16 bf16x8;
typedef __attribute__((ext_vector_type(4))) __bf16 bf16x4;
typedef __attribute__((ext_vector_type(4))) float  f32x4;

__device__ __forceinline__ __bf16 f2b(float f) { return (__bf16)f; }

// ---------------------------------------------------------------------------
// Kernel 1: gate_up = x_e @ w13_e ; h = silu(gate)*up  (bf16 out to ws)
// grid: (ID/BN, GT/BM, NE), block 256 (4 waves as 2x2)
// ---------------------------------------------------------------------------
__global__ __launch_bounds__(256, 2)
void moe_gemm1_swiglu(const float* __restrict__ x,
                      const float* __restrict__ w13,
                      __bf16* __restrict__ h) {
  __shared__ __bf16 As[BM][LDK];
  __shared__ __bf16 Bg[BN][LDK];
  __shared__ __bf16 Bu[BN][LDK];

  const int t  = threadIdx.x;
  const int e  = blockIdx.z;
  const int m0 = blockIdx.y * BM;
  const int n0 = blockIdx.x * BN;

  const float* xA = x   + (size_t)(e * GT + m0) * HD;
  const float* wB = w13 + (size_t)e * HD * (2 * ID);

  const int wid = t >> 6, lane = t & 63;
  const int wm = wid >> 1, wn = wid & 1;
  const int fr = lane & 15, fq = lane >> 4;

  f32x4 accg[4][4];
  f32x4 accu[4][4];
#pragma unroll
  for (int i = 0; i < 4; ++i)
#pragma unroll
    for (int j = 0; j < 4; ++j) { accg[i][j] = 0.f; accu[i][j] = 0.f; }

  // staging index precompute
  const int ar = (0 * 256 + t) >> 4;   // pattern: fid = i*256 + t

  for (int k0 = 0; k0 < HD; k0 += BK) {
    // ---- stage A: 128 x 64 f32 -> bf16 ----
    f32x4 va[8];
#pragma unroll
    for (int i = 0; i < 8; ++i) {
      int fid = i * 256 + t;
      int r = fid >> 4, c4 = fid & 15;
      va[i] = *reinterpret_cast<const f32x4*>(xA + (size_t)r * HD + k0 + c4 * 4);
    }
#pragma unroll
    for (int i = 0; i < 8; ++i) {
      int fid = i * 256 + t;
      int r = fid >> 4, c4 = fid & 15;
      bf16x4 b;
      b[0] = f2b(va[i][0]); b[1] = f2b(va[i][1]);
      b[2] = f2b(va[i][2]); b[3] = f2b(va[i][3]);
      *reinterpret_cast<bf16x4*>(&As[r][c4 * 4]) = b;
    }
    // ---- stage B (gate & up): 64k x 128n f32, transposed 4x4 blocks ----
#pragma unroll
    for (int i = 0; i < 2; ++i) {
      int bid = i * 256 + t;           // 0..511
      int kb = bid >> 5;               // 0..15  (k block of 4)
      int nb = bid & 31;               // 0..31  (n block of 4)
      const float* s0 = wB + (size_t)(k0 + kb * 4) * (2 * ID) + (n0 + nb * 4);
      f32x4 g0 = *reinterpret_cast<const f32x4*>(s0 + 0 * 2 * ID);
      f32x4 g1 = *reinterpret_cast<const f32x4*>(s0 + 1 * 2 * ID);
      f32x4 g2 = *reinterpret_cast<const f32x4*>(s0 + 2 * 2 * ID);
      f32x4 g3 = *reinterpret_cast<const f32x4*>(s0 + 3 * 2 * ID);
      const float* s1 = s0 + ID;
      f32x4 u0 = *reinterpret_cast<const f32x4*>(s1 + 0 * 2 * ID);
      f32x4 u1 = *reinterpret_cast<const f32x4*>(s1 + 1 * 2 * ID);
      f32x4 u2 = *reinterpret_cast<const f32x4*>(s1 + 2 * 2 * ID);
      f32x4 u3 = *reinterpret_cast<const f32x4*>(s1 + 3 * 2 * ID);
#pragma unroll
      for (int c = 0; c < 4; ++c) {
        bf16x4 bg;
        bg[0] = f2b(g0[c]); bg[1] = f2b(g1[c]);
        bg[2] = f2b(g2[c]); bg[3] = f2b(g3[c]);
        *reinterpret_cast<bf16x4*>(&Bg[nb * 4 + c][kb * 4]) = bg;
        bf16x4 bu;
        bu[0] = f2b(u0[c]); bu[1] = f2b(u1[c]);
        bu[2] = f2b(u2[c]); bu[3] = f2b(u3[c]);
        *reinterpret_cast<bf16x4*>(&Bu[nb * 4 + c][kb * 4]) = bu;
      }
    }
    __syncthreads();
    // ---- MFMA ----
#pragma unroll
    for (int kk = 0; kk < BK; kk += 32) {
      const int kof = kk + fq * 8;
      bf16x8 af[4], bgf[4], buf2[4];
#pragma unroll
      for (int mi = 0; mi < 4; ++mi)
        af[mi] = *reinterpret_cast<const bf16x8*>(&As[wm * 64 + mi * 16 + fr][kof]);
#pragma unroll
      for (int ni = 0; ni < 4; ++ni) {
        bgf[ni]  = *reinterpret_cast<const bf16x8*>(&Bg[wn * 64 + ni * 16 + fr][kof]);
        buf2[ni] = *reinterpret_cast<const bf16x8*>(&Bu[wn * 64 + ni * 16 + fr][kof]);
      }
#pragma unroll
      for (int mi = 0; mi < 4; ++mi)
#pragma unroll
        for (int ni = 0; ni < 4; ++ni) {
          accg[mi][ni] = __builtin_amdgcn_mfma_f32_16x16x32_bf16(af[mi], bgf[ni], accg[mi][ni], 0, 0, 0);
          accu[mi][ni] = __builtin_amdgcn_mfma_f32_16x16x32_bf16(af[mi], buf2[ni], accu[mi][ni], 0, 0, 0);
        }
    }
    __syncthreads();
  }

  // ---- epilogue: SwiGLU, write h (bf16) ----
#pragma unroll
  for (int mi = 0; mi < 4; ++mi)
#pragma unroll
    for (int ni = 0; ni < 4; ++ni)
#pragma unroll
      for (int j = 0; j < 4; ++j) {
        int row = m0 + wm * 64 + mi * 16 + fq * 4 + j;
        int col = n0 + wn * 64 + ni * 16 + fr;
        float g = accg[mi][ni][j];
        float u = accu[mi][ni][j];
        float s = g / (1.f + __expf(-g));
        h[(size_t)(e * GT + row) * ID + col] = f2b(s * u);
      }
}

// ---------------------------------------------------------------------------
// Kernel 2: out = h @ w2_e   (h bf16 [T][I], w2 f32 [E][I][H], out f32)
// grid: (HD/BN, GT/BM, NE), block 256
// ---------------------------------------------------------------------------
__global__ __launch_bounds__(256, 2)
void moe_gemm2(const __bf16* __restrict__ h,
               const float* __restrict__ w2,
               float* __restrict__ out) {
  __shared__ __bf16 As[BM][LDK];
  __shared__ __bf16 Bs[BN][LDK];

  const int t  = threadIdx.x;
  const int e  = blockIdx.z;
  const int m0 = blockIdx.y * BM;
  const int n0 = blockIdx.x * BN;

  const __bf16* hA = h  + (size_t)(e * GT + m0) * ID;
  const float*  wB = w2 + (size_t)e * ID * HD;

  const int wid = t >> 6, lane = t & 63;
  const int wm = wid >> 1, wn = wid & 1;
  const int fr = lane & 15, fq = lane >> 4;

  f32x4 acc[4][4];
#pragma unroll
  for (int i = 0; i < 4; ++i)
#pragma unroll
    for (int j = 0; j < 4; ++j) acc[i][j] = 0.f;

  for (int k0 = 0; k0 < ID; k0 += BK) {
    // ---- stage A: bf16 direct, 128 x 64 ----
#pragma unroll
    for (int i = 0; i < 4; ++i) {
      int fid = i * 256 + t;           // 0..1023
      int r = fid >> 3, c8 = fid & 7;  // 8x16B chunks per row
      bf16x8 v = *reinterpret_cast<const bf16x8*>(hA + (size_t)r * ID + k0 + c8 * 8);
      *reinterpret_cast<bf16x8*>(&As[r][c8 * 8]) = v;
    }
    // ---- stage B: 64k x 128n f32, transposed ----
#pragma unroll
    for (int i = 0; i < 2; ++i) {
      int bid = i * 256 + t;
      int kb = bid >> 5, nb = bid & 31;
      const float* s0 = wB + (size_t)(k0 + kb * 4) * HD + (n0 + nb * 4);
      f32x4 r0 = *reinterpret_cast<const f32x4*>(s0 + 0 * HD);
      f32x4 r1 = *reinterpret_cast<const f32x4*>(s0 + 1 * HD);
      f32x4 r2 = *reinterpret_cast<const f32x4*>(s0 + 2 * HD);
      f32x4 r3 = *reinterpret_cast<const f32x4*>(s0 + 3 * HD);
#pragma unroll
      for (int c = 0; c < 4; ++c) {
        bf16x4 b;
        b[0] = f2b(r0[c]); b[1] = f2b(r1[c]);
        b[2] = f2b(r2[c]); b[3] = f2b(r3[c]);
        *reinterpret_cast<bf16x4*>(&Bs[nb * 4 + c][kb * 4]) = b;
      }
    }
    __syncthreads();
#pragma unroll
    for (int kk = 0; kk < BK; kk += 32) {
      const int kof = kk + fq * 8;
      bf16x8 af[4], bf[4];
#pragma unroll
      for (int mi = 0; mi < 4; ++mi)
        af[mi] = *reinterpret_cast<const bf16x8*>(&As[wm * 64 + mi * 16 + fr][kof]);
#pragma unroll
      for (int ni = 0; ni < 4; ++ni)
        bf[ni] = *reinterpret_cast<const bf16x8*>(&Bs[wn * 64 + ni * 16 + fr][kof]);
#pragma unroll
      for (int mi = 0; mi < 4; ++mi)
#pragma unroll
        for (int ni = 0; ni < 4; ++ni)
          acc[mi][ni] = __builtin_amdgcn_mfma_f32_16x16x32_bf16(af[mi], bf[ni], acc[mi][ni], 0, 0, 0);
    }
    __syncthreads();
  }

  // ---- epilogue: f32 store ----
#pragma unroll
  for (int mi = 0; mi < 4; ++mi)
#pragma unroll
    for (int ni = 0; ni < 4; ++ni)
#pragma unroll
      for (int j = 0; j < 4; ++j) {
        int row = m0 + wm * 64 + mi * 16 + fq * 4 + j;
        int col = n0 + wn * 64 + ni * 16 + fr;
        out[(size_t)(e * GT + row) * HD + col] = acc[mi][ni][j];
      }
}

extern "C" void kernel_launch(void* const* d_in, const int* in_sizes, int n_in,
                              void* d_out, int out_size, void* d_ws, size_t ws_size,
                              hipStream_t stream) {
  const float* x   = (const float*)d_in[0];
  const float* w13 = (const float*)d_in[1];
  const float* w2  = (const float*)d_in[2];
  float* out = (float*)d_out;
  __bf16* h = (__bf16*)d_ws;   // T x I bf16 = 64 MiB scratch

  dim3 blk(256);
  moe_gemm1_swiglu<<<dim3(ID / BN, GT / BM, NE), blk, 0, stream>>>(x, w13, h);
  moe_gemm2<<<dim3(HD / BN, GT / BM, NE), blk, 0, stream>>>(h, w2, out);
}